// Round 1
// baseline (317.702 us; speedup 1.0000x reference)
//
#include <hip/hip_runtime.h>
#include <math.h>

#define HWDIM 96
#define NPIX (HWDIM*HWDIM)     // 9216
#define BATCH 2
#define CIN 64
#define CCAT 128

// ---------------------------------------------------------------------------
// Kernel 1: transpose weights (co,ci,kh,kw) -> wT[co][kh][kw][ci], co in 0..255
// co 0..63 = wq, 64..127 = wk, 128..255 = wv
// ---------------------------------------------------------------------------
__global__ void wt_kernel(const float* __restrict__ wq,
                          const float* __restrict__ wk,
                          const float* __restrict__ wv,
                          float* __restrict__ wT) {
    int idx = blockIdx.x * 256 + threadIdx.x;   // 256*576 = 147456
    if (idx >= 256 * 576) return;
    int co  = idx / 576;
    int rem = idx % 576;
    int ci  = rem / 9;
    int t   = rem % 9;      // kh*3+kw
    float val;
    if (co < 64)        val = wq[(co * 64 + ci) * 9 + t];
    else if (co < 128)  val = wk[((co - 64) * 64 + ci) * 9 + t];
    else                val = wv[((co - 128) * 64 + ci) * 9 + t];
    wT[(co * 9 + t) * 64 + ci] = val;
}

// ---------------------------------------------------------------------------
// Kernel 2: positional encoding -> channels 64..127 of Qcat and Kcat
// pe channels: [0,16) sin(h*f_j) j=c; [16,32) cos(h*f_{c-16});
//              [32,48) sin(w*f_{c-32}); [48,64) cos(w*f_{c-48});
// f_j = 10000^(-j/16) = exp2(-j * log2(10000)/16)
// ---------------------------------------------------------------------------
__global__ void pe_kernel(float* __restrict__ Qcat, float* __restrict__ Kcat) {
    int idx = blockIdx.x * 256 + threadIdx.x;   // B*NPIX*64 = 1179648
    if (idx >= BATCH * NPIX * 64) return;
    int c   = idx & 63;
    int pix = idx >> 6;          // b*NPIX + h*96 + w
    int p   = pix % NPIX;
    int h   = p / HWDIM;
    int w   = p % HWDIM;
    int pos = (c < 32) ? h : w;
    int j   = c & 15;
    float f   = exp2f(-(float)j * 0.83048202372184059f);  // log2(10000)/16
    float ang = (float)pos * f;
    float val = ((c & 16) == 0) ? sinf(ang) : cosf(ang);
    int off = pix * CCAT + 64 + c;
    Qcat[off] = val;
    Kcat[off] = val;
}

// ---------------------------------------------------------------------------
// Kernel 3: direct 3x3 conv, stride 1, pad 1.
// grid.x = 72 (b * 6x6 tiles of 16x16), grid.y = 32 (8-co chunks of 256 co)
// LDS: x tile [18][18][36] (ci padded 32->36), two ci-halves.
// ---------------------------------------------------------------------------
__global__ __launch_bounds__(256) void conv_kernel(
        const float* __restrict__ x, const float* __restrict__ wT,
        const float* __restrict__ bq, const float* __restrict__ bk,
        const float* __restrict__ bv,
        float* __restrict__ Qcat, float* __restrict__ Kcat,
        float* __restrict__ V) {
    __shared__ float xs[18 * 18 * 36];
    int t   = blockIdx.x;            // 0..71
    int b   = t / 36;
    int tt  = t % 36;
    int ty0 = (tt / 6) * 16;
    int tx0 = (tt % 6) * 16;
    int co0 = blockIdx.y * 8;
    int tid = threadIdx.x;
    int ty  = tid / 16;
    int tx  = tid % 16;

    float acc[8] = {0.f, 0.f, 0.f, 0.f, 0.f, 0.f, 0.f, 0.f};

    for (int half = 0; half < 2; ++half) {
        int cbase = half * 32;
        __syncthreads();   // protect xs reuse
        // stage 32 channels x 18x18 into LDS
        for (int pp = tid; pp < 18 * 18 * 32; pp += 256) {
            int ci  = pp / 324;
            int rem = pp % 324;
            int y   = rem / 18;
            int xx  = rem % 18;
            int iy  = ty0 + y - 1;
            int ix  = tx0 + xx - 1;
            float v = 0.f;
            if (iy >= 0 && iy < HWDIM && ix >= 0 && ix < HWDIM)
                v = x[((b * CIN + cbase + ci) * HWDIM + iy) * HWDIM + ix];
            xs[(y * 18 + xx) * 36 + ci] = v;
        }
        __syncthreads();

        for (int kh = 0; kh < 3; ++kh) {
            for (int kw = 0; kw < 3; ++kw) {
                const float* xp = &xs[((ty + kh) * 18 + tx + kw) * 36];
                const float* wp = &wT[(co0 * 9 + kh * 3 + kw) * 64 + cbase];
                #pragma unroll
                for (int c4 = 0; c4 < 32; c4 += 4) {
                    float4 xv = *(const float4*)&xp[c4];
                    #pragma unroll
                    for (int c = 0; c < 8; ++c) {
                        float4 wv4 = *(const float4*)&wp[c * 576 + c4];
                        acc[c] = fmaf(xv.x, wv4.x, acc[c]);
                        acc[c] = fmaf(xv.y, wv4.y, acc[c]);
                        acc[c] = fmaf(xv.z, wv4.z, acc[c]);
                        acc[c] = fmaf(xv.w, wv4.w, acc[c]);
                    }
                }
            }
        }
    }

    // epilogue
    int gy  = ty0 + ty;
    int gx  = tx0 + tx;
    int pix = b * NPIX + gy * HWDIM + gx;
    float* dst;
    const float* bias;
    int cb;
    if (co0 < 64)       { dst = Qcat; bias = bq; cb = co0; }
    else if (co0 < 128) { dst = Kcat; bias = bk; cb = co0 - 64; }
    else                { dst = V;    bias = bv; cb = co0 - 128; }
    float* o = dst + pix * CCAT + cb;
    #pragma unroll
    for (int c = 0; c < 8; ++c) o[c] = acc[c] + bias[cb + c];
}

// ---------------------------------------------------------------------------
// Kernel 4: neighborhood attention, K=7, D=2. One wave per pixel.
// Phase 1: lane = neighbor (49 of 64 active): logit = q . k_n
// Phase 2: wave softmax via shfl_xor
// Phase 3: lane = 2 channels: o[2l..2l+1] = sum_n p_n * v_n
// ---------------------------------------------------------------------------
__global__ __launch_bounds__(256) void natt_kernel(
        const float* __restrict__ Qcat, const float* __restrict__ Kcat,
        const float* __restrict__ V, float* __restrict__ out) {
    __shared__ float qs[4][CCAT];
    int wv   = threadIdx.x >> 6;
    int lane = threadIdx.x & 63;
    int p    = blockIdx.x * 4 + wv;     // < 18432
    int b    = p / NPIX;
    int pix  = p % NPIX;
    int h    = pix / HWDIM;
    int w    = pix % HWDIM;

    // stage q (128 floats) into LDS
    const float* qp = Qcat + p * CCAT;
    qs[wv][lane]      = qp[lane];
    qs[wv][lane + 64] = qp[lane + 64];

    // neighbor index for this lane (clamped for lanes >= 49)
    int nn = lane < 49 ? lane : 48;
    int i  = nn / 7;
    int j  = nn % 7;
    int gh = h & 1, rh = h >> 1;
    int sh = rh - 3; sh = sh < 0 ? 0 : (sh > 41 ? 41 : sh);
    int nh = gh + (sh + i) * 2;
    int gw = w & 1, rw = w >> 1;
    int sw = rw - 3; sw = sw < 0 ? 0 : (sw > 41 ? 41 : sw);
    int nw = gw + (sw + j) * 2;
    int noff = b * NPIX + nh * HWDIM + nw;

    __syncthreads();

    // phase 1: logits
    const float* kp = Kcat + noff * CCAT;
    float acc = 0.f;
    #pragma unroll
    for (int c = 0; c < CCAT; c += 4) {
        float4 q4 = *(const float4*)&qs[wv][c];
        float4 k4 = *(const float4*)&kp[c];
        acc = fmaf(q4.x, k4.x, acc);
        acc = fmaf(q4.y, k4.y, acc);
        acc = fmaf(q4.z, k4.z, acc);
        acc = fmaf(q4.w, k4.w, acc);
    }
    float logit = (lane < 49) ? acc * 0.08838834764831845f : -INFINITY;

    // phase 2: softmax across the wave
    float m = logit;
    #pragma unroll
    for (int off = 32; off > 0; off >>= 1) m = fmaxf(m, __shfl_xor(m, off));
    float e = (lane < 49) ? expf(logit - m) : 0.f;
    float s = e;
    #pragma unroll
    for (int off = 32; off > 0; off >>= 1) s += __shfl_xor(s, off);
    float pr = e / s;

    // phase 3: PV, lane owns channels 2l, 2l+1
    float2 o = make_float2(0.f, 0.f);
    int myc = lane << 1;
    for (int n = 0; n < 49; ++n) {
        float pn = __shfl(pr, n);
        int   on = __shfl(noff, n);
        float2 v2 = *(const float2*)&V[on * CCAT + myc];
        o.x = fmaf(pn, v2.x, o.x);
        o.y = fmaf(pn, v2.y, o.y);
    }
    float* op = out + p * CCAT + myc;
    op[0] = o.x;
    op[1] = o.y;
}

// ---------------------------------------------------------------------------
extern "C" void kernel_launch(void* const* d_in, const int* in_sizes, int n_in,
                              void* d_out, int out_size, void* d_ws, size_t ws_size,
                              hipStream_t stream) {
    const float* x  = (const float*)d_in[0];
    const float* wq = (const float*)d_in[1];
    const float* bq = (const float*)d_in[2];
    const float* wk = (const float*)d_in[3];
    const float* bk = (const float*)d_in[4];
    const float* wv = (const float*)d_in[5];
    const float* bv = (const float*)d_in[6];

    float* ws   = (float*)d_ws;
    float* Qcat = ws;                        // B*NPIX*128 = 2359296 floats
    float* Kcat = Qcat + BATCH * NPIX * CCAT;
    float* V    = Kcat + BATCH * NPIX * CCAT;
    float* wT   = V    + BATCH * NPIX * CCAT; // 147456 floats

    hipLaunchKernelGGL(wt_kernel, dim3(576), dim3(256), 0, stream, wq, wk, wv, wT);
    hipLaunchKernelGGL(pe_kernel, dim3(4608), dim3(256), 0, stream, Qcat, Kcat);
    hipLaunchKernelGGL(conv_kernel, dim3(72, 32), dim3(256), 0, stream,
                       x, wT, bq, bk, bv, Qcat, Kcat, V);
    hipLaunchKernelGGL(natt_kernel, dim3(4608), dim3(256), 0, stream,
                       Qcat, Kcat, V, (float*)d_out);
}

// Round 2
// 113.713 us; speedup vs baseline: 2.7939x; 2.7939x over previous
//
#include <hip/hip_runtime.h>
#include <math.h>

#define HWDIM 96
#define NPIX (HWDIM*HWDIM)     // 9216
#define BATCH 2
#define CIN 64
#define CCAT 128
#define PADW 98                // 96 + 2 halo

typedef __attribute__((ext_vector_type(8))) short bf16x8;
typedef __attribute__((ext_vector_type(4))) float f32x4;

__device__ __forceinline__ unsigned short f2bf(float f) {
    unsigned u = __builtin_bit_cast(unsigned, f);
    unsigned r = (u + 0x7FFFu + ((u >> 16) & 1u)) >> 16;
    return (unsigned short)r;
}
__device__ __forceinline__ float bf2f(unsigned short h) {
    unsigned u = ((unsigned)h) << 16;
    return __builtin_bit_cast(float, u);
}

// ---------------------------------------------------------------------------
// Kernel 0: pad + NCHW->NHWC + f32->bf16:  xp[b][hp][wp][ci], hp/wp in [0,98)
// zero at hp==0,97 / wp==0,97. One block per (b, hp).
// ---------------------------------------------------------------------------
__global__ __launch_bounds__(256) void pad_kernel(const float* __restrict__ x,
                                                  unsigned short* __restrict__ xp) {
    __shared__ float xls[64][97];   // 97 pad: stride 97 mod 32 = 1, conflict-free
    int b  = blockIdx.x / PADW;
    int hp = blockIdx.x % PADW;
    int tid = threadIdx.x;
    bool interior = (hp >= 1 && hp <= HWDIM);
    if (interior) {
        int h = hp - 1;
        for (int idx = tid; idx < 64 * HWDIM; idx += 256) {
            int ci = idx / HWDIM;
            int w  = idx % HWDIM;
            xls[ci][w] = x[((b * CIN + ci) * HWDIM + h) * HWDIM + w];
        }
    }
    __syncthreads();
    for (int idx = tid; idx < PADW * 64; idx += 256) {
        int wp = idx / 64;
        int ci = idx % 64;
        float v = 0.f;
        if (interior && wp >= 1 && wp <= HWDIM) v = xls[ci][wp - 1];
        xp[((b * PADW + hp) * PADW + wp) * 64 + ci] = f2bf(v);
    }
}

// ---------------------------------------------------------------------------
// Kernel 1: weights -> bf16 wbT[t][co][ci], t = kh*3+kw, co: 0..63 q, 64..127 k,
// 128..255 v.
// ---------------------------------------------------------------------------
__global__ void wb_kernel(const float* __restrict__ wq,
                          const float* __restrict__ wk,
                          const float* __restrict__ wv,
                          unsigned short* __restrict__ wbT) {
    int idx = blockIdx.x * 256 + threadIdx.x;   // 9*256*64 = 147456
    if (idx >= 9 * 256 * 64) return;
    int t   = idx / (256 * 64);
    int rem = idx % (256 * 64);
    int co  = rem / 64;
    int ci  = rem % 64;
    float val;
    if (co < 64)        val = wq[(co * 64 + ci) * 9 + t];
    else if (co < 128)  val = wk[((co - 64) * 64 + ci) * 9 + t];
    else                val = wv[((co - 128) * 64 + ci) * 9 + t];
    wbT[(t * 256 + co) * 64 + ci] = f2bf(val);
}

// ---------------------------------------------------------------------------
// Kernel 2: positional encoding -> channels 64..127 of Qcat and Kcat
// ---------------------------------------------------------------------------
__global__ void pe_kernel(float* __restrict__ Qcat, float* __restrict__ Kcat) {
    int idx = blockIdx.x * 256 + threadIdx.x;   // B*NPIX*64
    if (idx >= BATCH * NPIX * 64) return;
    int c   = idx & 63;
    int pix = idx >> 6;
    int p   = pix % NPIX;
    int h   = p / HWDIM;
    int w   = p % HWDIM;
    int pos = (c < 32) ? h : w;
    int j   = c & 15;
    float f   = exp2f(-(float)j * 0.83048202372184059f);  // log2(10000)/16
    float ang = (float)pos * f;
    float val = ((c & 16) == 0) ? sinf(ang) : cosf(ang);
    int off = pix * CCAT + 64 + c;
    Qcat[off] = val;
    Kcat[off] = val;
}

// ---------------------------------------------------------------------------
// Kernel 3: conv via tap-decomposed implicit GEMM, bf16 MFMA 16x16x32.
// grid = (192, 2): blockIdx.x -> (b, output row h); blockIdx.y -> co chunk 128.
// Block stages padded rows h..h+2 (image rows h-1..h+1) once in LDS; each tap
// (kh,kw) is just an LDS base offset. 4 waves, each computes M48 x N64.
// ---------------------------------------------------------------------------
__global__ __launch_bounds__(256) void conv_mfma(
        const unsigned short* __restrict__ xp,
        const unsigned short* __restrict__ wbT,
        const float* __restrict__ bq, const float* __restrict__ bk,
        const float* __restrict__ bv,
        float* __restrict__ Qcat, float* __restrict__ Kcat,
        unsigned short* __restrict__ Vb) {
    __shared__ unsigned short xs[3 * PADW * 72];   // ci padded 64->72, 42336 B
    int b   = blockIdx.x / HWDIM;
    int h   = blockIdx.x % HWDIM;
    int co0 = blockIdx.y * 128;
    int tid = threadIdx.x;

    // stage 3 padded rows (16B per thread-iter)
    for (int i = tid; i < 3 * PADW * 8; i += 256) {
        int r   = i / (PADW * 8);
        int rem = i % (PADW * 8);
        int wp  = rem / 8;
        int c8  = rem % 8;
        const uint4* src = (const uint4*)&xp[(((b * PADW) + h + r) * PADW + wp) * 64 + c8 * 8];
        *(uint4*)&xs[(r * PADW + wp) * 72 + c8 * 8] = *src;
    }
    __syncthreads();

    int lane = tid & 63;
    int wv   = tid >> 6;
    int mw   = wv >> 1;          // 0..1 : w half
    int nw   = wv & 1;           // 0..1 : co 64-chunk
    int lw   = lane & 15;
    int ksub = (lane >> 4) * 8;

    f32x4 acc[3][4];
    #pragma unroll
    for (int m = 0; m < 3; ++m)
        #pragma unroll
        for (int n = 0; n < 4; ++n) acc[m][n] = (f32x4){0.f, 0.f, 0.f, 0.f};

    #pragma unroll
    for (int t = 0; t < 9; ++t) {
        int kh = t / 3, kw = t % 3;
        #pragma unroll
        for (int half = 0; half < 2; ++half) {
            const unsigned short* ap = xs + kh * (PADW * 72)
                                     + (mw * 48 + lw + kw) * 72 + half * 32 + ksub;
            bf16x8 A0 = *(const bf16x8*)(ap);
            bf16x8 A1 = *(const bf16x8*)(ap + 16 * 72);
            bf16x8 A2 = *(const bf16x8*)(ap + 32 * 72);
            const unsigned short* bp = wbT + ((t * 256 + co0 + nw * 64 + lw) * 64)
                                     + half * 32 + ksub;
            bf16x8 B0 = *(const bf16x8*)(bp);
            bf16x8 B1 = *(const bf16x8*)(bp + 16 * 64);
            bf16x8 B2 = *(const bf16x8*)(bp + 32 * 64);
            bf16x8 B3 = *(const bf16x8*)(bp + 48 * 64);
            acc[0][0] = __builtin_amdgcn_mfma_f32_16x16x32_bf16(A0, B0, acc[0][0], 0, 0, 0);
            acc[0][1] = __builtin_amdgcn_mfma_f32_16x16x32_bf16(A0, B1, acc[0][1], 0, 0, 0);
            acc[0][2] = __builtin_amdgcn_mfma_f32_16x16x32_bf16(A0, B2, acc[0][2], 0, 0, 0);
            acc[0][3] = __builtin_amdgcn_mfma_f32_16x16x32_bf16(A0, B3, acc[0][3], 0, 0, 0);
            acc[1][0] = __builtin_amdgcn_mfma_f32_16x16x32_bf16(A1, B0, acc[1][0], 0, 0, 0);
            acc[1][1] = __builtin_amdgcn_mfma_f32_16x16x32_bf16(A1, B1, acc[1][1], 0, 0, 0);
            acc[1][2] = __builtin_amdgcn_mfma_f32_16x16x32_bf16(A1, B2, acc[1][2], 0, 0, 0);
            acc[1][3] = __builtin_amdgcn_mfma_f32_16x16x32_bf16(A1, B3, acc[1][3], 0, 0, 0);
            acc[2][0] = __builtin_amdgcn_mfma_f32_16x16x32_bf16(A2, B0, acc[2][0], 0, 0, 0);
            acc[2][1] = __builtin_amdgcn_mfma_f32_16x16x32_bf16(A2, B1, acc[2][1], 0, 0, 0);
            acc[2][2] = __builtin_amdgcn_mfma_f32_16x16x32_bf16(A2, B2, acc[2][2], 0, 0, 0);
            acc[2][3] = __builtin_amdgcn_mfma_f32_16x16x32_bf16(A2, B3, acc[2][3], 0, 0, 0);
        }
    }

    // epilogue: route co chunks to Qcat / Kcat / Vb(bf16), add bias
    #pragma unroll
    for (int n = 0; n < 4; ++n) {
        int cg   = co0 + nw * 64 + n * 16;   // wave-uniform 16-aligned chunk base
        int co_f = cg + lw;
        #pragma unroll
        for (int m = 0; m < 3; ++m) {
            int wbase = mw * 48 + m * 16 + ((lane >> 4) << 2);
            if (cg < 64) {
                float bval = bq[co_f];
                #pragma unroll
                for (int r = 0; r < 4; ++r) {
                    int pix = b * NPIX + h * HWDIM + wbase + r;
                    Qcat[pix * CCAT + co_f] = acc[m][n][r] + bval;
                }
            } else if (cg < 128) {
                int ch = co_f - 64;
                float bval = bk[ch];
                #pragma unroll
                for (int r = 0; r < 4; ++r) {
                    int pix = b * NPIX + h * HWDIM + wbase + r;
                    Kcat[pix * CCAT + ch] = acc[m][n][r] + bval;
                }
            } else {
                int ch = co_f - 128;
                float bval = bv[ch];
                #pragma unroll
                for (int r = 0; r < 4; ++r) {
                    int pix = b * NPIX + h * HWDIM + wbase + r;
                    Vb[pix * CCAT + ch] = f2bf(acc[m][n][r] + bval);
                }
            }
        }
    }
}

// ---------------------------------------------------------------------------
// Kernel 4: neighborhood attention, K=7, D=2. One wave per pixel. V is bf16.
// ---------------------------------------------------------------------------
__global__ __launch_bounds__(256) void natt_kernel(
        const float* __restrict__ Qcat, const float* __restrict__ Kcat,
        const unsigned short* __restrict__ Vb, float* __restrict__ out) {
    __shared__ float qs[4][CCAT];
    int wv   = threadIdx.x >> 6;
    int lane = threadIdx.x & 63;
    int p    = blockIdx.x * 4 + wv;     // < 18432
    int b    = p / NPIX;
    int pix  = p % NPIX;
    int h    = pix / HWDIM;
    int w    = pix % HWDIM;

    const float* qp = Qcat + p * CCAT;
    qs[wv][lane]      = qp[lane];
    qs[wv][lane + 64] = qp[lane + 64];

    int nn = lane < 49 ? lane : 48;
    int i  = nn / 7;
    int j  = nn % 7;
    int gh = h & 1, rh = h >> 1;
    int sh = rh - 3; sh = sh < 0 ? 0 : (sh > 41 ? 41 : sh);
    int nh = gh + (sh + i) * 2;
    int gw = w & 1, rw = w >> 1;
    int sw = rw - 3; sw = sw < 0 ? 0 : (sw > 41 ? 41 : sw);
    int nw = gw + (sw + j) * 2;
    int noff = b * NPIX + nh * HWDIM + nw;

    __syncthreads();

    const float* kp = Kcat + noff * CCAT;
    float acc = 0.f;
    #pragma unroll
    for (int c = 0; c < CCAT; c += 4) {
        float4 q4 = *(const float4*)&qs[wv][c];
        float4 k4 = *(const float4*)&kp[c];
        acc = fmaf(q4.x, k4.x, acc);
        acc = fmaf(q4.y, k4.y, acc);
        acc = fmaf(q4.z, k4.z, acc);
        acc = fmaf(q4.w, k4.w, acc);
    }
    float logit = (lane < 49) ? acc * 0.08838834764831845f : -INFINITY;

    float m = logit;
    #pragma unroll
    for (int off = 32; off > 0; off >>= 1) m = fmaxf(m, __shfl_xor(m, off));
    float e = (lane < 49) ? expf(logit - m) : 0.f;
    float s = e;
    #pragma unroll
    for (int off = 32; off > 0; off >>= 1) s += __shfl_xor(s, off);
    float pr = e / s;

    float2 o = make_float2(0.f, 0.f);
    int myc = lane << 1;
    for (int n = 0; n < 49; ++n) {
        float pn = __shfl(pr, n);
        int   on = __shfl(noff, n);
        unsigned v2 = *(const unsigned*)&Vb[on * CCAT + myc];
        float vx = bf2f((unsigned short)(v2 & 0xFFFF));
        float vy = bf2f((unsigned short)(v2 >> 16));
        o.x = fmaf(pn, vx, o.x);
        o.y = fmaf(pn, vy, o.y);
    }
    float* op = out + p * CCAT + myc;
    op[0] = o.x;
    op[1] = o.y;
}

// ---------------------------------------------------------------------------
extern "C" void kernel_launch(void* const* d_in, const int* in_sizes, int n_in,
                              void* d_out, int out_size, void* d_ws, size_t ws_size,
                              hipStream_t stream) {
    const float* x  = (const float*)d_in[0];
    const float* wq = (const float*)d_in[1];
    const float* bq = (const float*)d_in[2];
    const float* wk = (const float*)d_in[3];
    const float* bk = (const float*)d_in[4];
    const float* wv = (const float*)d_in[5];
    const float* bv = (const float*)d_in[6];

    float* ws   = (float*)d_ws;
    float* Qcat = ws;                                  // 2359296 f32
    float* Kcat = Qcat + BATCH * NPIX * CCAT;          // 2359296 f32
    unsigned short* Vb  = (unsigned short*)(Kcat + BATCH * NPIX * CCAT); // 2359296 bf16
    unsigned short* xp  = Vb + BATCH * NPIX * CCAT;    // 2*98*98*64 bf16
    unsigned short* wbT = xp + BATCH * PADW * PADW * 64; // 147456 bf16

    hipLaunchKernelGGL(pad_kernel, dim3(BATCH * PADW), dim3(256), 0, stream, x, xp);
    hipLaunchKernelGGL(wb_kernel, dim3(576), dim3(256), 0, stream, wq, wk, wv, wbT);
    hipLaunchKernelGGL(pe_kernel, dim3(4608), dim3(256), 0, stream, Qcat, Kcat);
    hipLaunchKernelGGL(conv_mfma, dim3(192, 2), dim3(256), 0, stream,
                       xp, wbT, bq, bk, bv, Qcat, Kcat, Vb);
    hipLaunchKernelGGL(natt_kernel, dim3(4608), dim3(256), 0, stream,
                       Qcat, Kcat, Vb, (float*)d_out);
}

// Round 3
// 71.806 us; speedup vs baseline: 4.4244x; 1.5836x over previous
//
#include <hip/hip_runtime.h>
#include <math.h>

#define HWDIM 96
#define NPIX (HWDIM*HWDIM)     // 9216
#define BATCH 2
#define CIN 64
#define CCAT 128
#define PADW 98                // 96 + 2 halo

typedef __attribute__((ext_vector_type(8))) short bf16x8;
typedef __attribute__((ext_vector_type(4))) float f32x4;

__device__ __forceinline__ unsigned short f2bf(float f) {
    unsigned u = __builtin_bit_cast(unsigned, f);
    unsigned r = (u + 0x7FFFu + ((u >> 16) & 1u)) >> 16;
    return (unsigned short)r;
}
__device__ __forceinline__ float bflo(unsigned u) {
    return __builtin_bit_cast(float, u << 16);
}
__device__ __forceinline__ float bfhi(unsigned u) {
    return __builtin_bit_cast(float, u & 0xFFFF0000u);
}

// ---------------------------------------------------------------------------
// Kernel 0: pad + NCHW->NHWC + f32->bf16:  xp[b][hp][wp][ci]
// ---------------------------------------------------------------------------
__global__ __launch_bounds__(256) void pad_kernel(const float* __restrict__ x,
                                                  unsigned short* __restrict__ xp) {
    __shared__ float xls[64][97];
    int b  = blockIdx.x / PADW;
    int hp = blockIdx.x % PADW;
    int tid = threadIdx.x;
    bool interior = (hp >= 1 && hp <= HWDIM);
    if (interior) {
        int h = hp - 1;
        for (int idx = tid; idx < 64 * HWDIM; idx += 256) {
            int ci = idx / HWDIM;
            int w  = idx % HWDIM;
            xls[ci][w] = x[((b * CIN + ci) * HWDIM + h) * HWDIM + w];
        }
    }
    __syncthreads();
    for (int idx = tid; idx < PADW * 64; idx += 256) {
        int wp = idx / 64;
        int ci = idx % 64;
        float v = 0.f;
        if (interior && wp >= 1 && wp <= HWDIM) v = xls[ci][wp - 1];
        xp[((b * PADW + hp) * PADW + wp) * 64 + ci] = f2bf(v);
    }
}

// ---------------------------------------------------------------------------
// Kernel 1: weights -> bf16 wbT[t][co][ci]
// ---------------------------------------------------------------------------
__global__ void wb_kernel(const float* __restrict__ wq,
                          const float* __restrict__ wk,
                          const float* __restrict__ wv,
                          unsigned short* __restrict__ wbT) {
    int idx = blockIdx.x * 256 + threadIdx.x;
    if (idx >= 9 * 256 * 64) return;
    int t   = idx / (256 * 64);
    int rem = idx % (256 * 64);
    int co  = rem / 64;
    int ci  = rem % 64;
    float val;
    if (co < 64)        val = wq[(co * 64 + ci) * 9 + t];
    else if (co < 128)  val = wk[((co - 64) * 64 + ci) * 9 + t];
    else                val = wv[((co - 128) * 64 + ci) * 9 + t];
    wbT[(t * 256 + co) * 64 + ci] = f2bf(val);
}

// ---------------------------------------------------------------------------
// Kernel 2: positional encoding -> bf16 channels 64..127 of Qb and Kb
// ---------------------------------------------------------------------------
__global__ void pe_kernel(unsigned short* __restrict__ Qb,
                          unsigned short* __restrict__ Kb) {
    int idx = blockIdx.x * 256 + threadIdx.x;
    if (idx >= BATCH * NPIX * 64) return;
    int c   = idx & 63;
    int pix = idx >> 6;
    int p   = pix % NPIX;
    int h   = p / HWDIM;
    int w   = p % HWDIM;
    int pos = (c < 32) ? h : w;
    int j   = c & 15;
    float f   = exp2f(-(float)j * 0.83048202372184059f);
    float ang = (float)pos * f;
    float val = ((c & 16) == 0) ? sinf(ang) : cosf(ang);
    unsigned short bv = f2bf(val);
    int off = pix * CCAT + 64 + c;
    Qb[off] = bv;
    Kb[off] = bv;
}

// ---------------------------------------------------------------------------
// Kernel 3: conv via tap-decomposed implicit GEMM, bf16 MFMA 16x16x32.
// ---------------------------------------------------------------------------
__global__ __launch_bounds__(256) void conv_mfma(
        const unsigned short* __restrict__ xp,
        const unsigned short* __restrict__ wbT,
        const float* __restrict__ bq, const float* __restrict__ bk,
        const float* __restrict__ bv,
        unsigned short* __restrict__ Qb, unsigned short* __restrict__ Kb,
        unsigned short* __restrict__ Vb) {
    __shared__ unsigned short xs[3 * PADW * 72];
    int b   = blockIdx.x / HWDIM;
    int h   = blockIdx.x % HWDIM;
    int co0 = blockIdx.y * 128;
    int tid = threadIdx.x;

    for (int i = tid; i < 3 * PADW * 8; i += 256) {
        int r   = i / (PADW * 8);
        int rem = i % (PADW * 8);
        int wp  = rem / 8;
        int c8  = rem % 8;
        const uint4* src = (const uint4*)&xp[(((b * PADW) + h + r) * PADW + wp) * 64 + c8 * 8];
        *(uint4*)&xs[(r * PADW + wp) * 72 + c8 * 8] = *src;
    }
    __syncthreads();

    int lane = tid & 63;
    int wv   = tid >> 6;
    int mw   = wv >> 1;
    int nw   = wv & 1;
    int lw   = lane & 15;
    int ksub = (lane >> 4) * 8;

    f32x4 acc[3][4];
    #pragma unroll
    for (int m = 0; m < 3; ++m)
        #pragma unroll
        for (int n = 0; n < 4; ++n) acc[m][n] = (f32x4){0.f, 0.f, 0.f, 0.f};

    #pragma unroll
    for (int t = 0; t < 9; ++t) {
        int kh = t / 3, kw = t % 3;
        #pragma unroll
        for (int half = 0; half < 2; ++half) {
            const unsigned short* ap = xs + kh * (PADW * 72)
                                     + (mw * 48 + lw + kw) * 72 + half * 32 + ksub;
            bf16x8 A0 = *(const bf16x8*)(ap);
            bf16x8 A1 = *(const bf16x8*)(ap + 16 * 72);
            bf16x8 A2 = *(const bf16x8*)(ap + 32 * 72);
            const unsigned short* bp = wbT + ((t * 256 + co0 + nw * 64 + lw) * 64)
                                     + half * 32 + ksub;
            bf16x8 B0 = *(const bf16x8*)(bp);
            bf16x8 B1 = *(const bf16x8*)(bp + 16 * 64);
            bf16x8 B2 = *(const bf16x8*)(bp + 32 * 64);
            bf16x8 B3 = *(const bf16x8*)(bp + 48 * 64);
            acc[0][0] = __builtin_amdgcn_mfma_f32_16x16x32_bf16(A0, B0, acc[0][0], 0, 0, 0);
            acc[0][1] = __builtin_amdgcn_mfma_f32_16x16x32_bf16(A0, B1, acc[0][1], 0, 0, 0);
            acc[0][2] = __builtin_amdgcn_mfma_f32_16x16x32_bf16(A0, B2, acc[0][2], 0, 0, 0);
            acc[0][3] = __builtin_amdgcn_mfma_f32_16x16x32_bf16(A0, B3, acc[0][3], 0, 0, 0);
            acc[1][0] = __builtin_amdgcn_mfma_f32_16x16x32_bf16(A1, B0, acc[1][0], 0, 0, 0);
            acc[1][1] = __builtin_amdgcn_mfma_f32_16x16x32_bf16(A1, B1, acc[1][1], 0, 0, 0);
            acc[1][2] = __builtin_amdgcn_mfma_f32_16x16x32_bf16(A1, B2, acc[1][2], 0, 0, 0);
            acc[1][3] = __builtin_amdgcn_mfma_f32_16x16x32_bf16(A1, B3, acc[1][3], 0, 0, 0);
            acc[2][0] = __builtin_amdgcn_mfma_f32_16x16x32_bf16(A2, B0, acc[2][0], 0, 0, 0);
            acc[2][1] = __builtin_amdgcn_mfma_f32_16x16x32_bf16(A2, B1, acc[2][1], 0, 0, 0);
            acc[2][2] = __builtin_amdgcn_mfma_f32_16x16x32_bf16(A2, B2, acc[2][2], 0, 0, 0);
            acc[2][3] = __builtin_amdgcn_mfma_f32_16x16x32_bf16(A2, B3, acc[2][3], 0, 0, 0);
        }
    }

    #pragma unroll
    for (int n = 0; n < 4; ++n) {
        int cg   = co0 + nw * 64 + n * 16;
        int co_f = cg + lw;
        #pragma unroll
        for (int m = 0; m < 3; ++m) {
            int wbase = mw * 48 + m * 16 + ((lane >> 4) << 2);
            if (cg < 64) {
                float bval = bq[co_f];
                #pragma unroll
                for (int r = 0; r < 4; ++r) {
                    int pix = b * NPIX + h * HWDIM + wbase + r;
                    Qb[pix * CCAT + co_f] = f2bf(acc[m][n][r] + bval);
                }
            } else if (cg < 128) {
                int ch = co_f - 64;
                float bval = bk[ch];
                #pragma unroll
                for (int r = 0; r < 4; ++r) {
                    int pix = b * NPIX + h * HWDIM + wbase + r;
                    Kb[pix * CCAT + ch] = f2bf(acc[m][n][r] + bval);
                }
            } else {
                int ch = co_f - 128;
                float bval = bv[ch];
                #pragma unroll
                for (int r = 0; r < 4; ++r) {
                    int pix = b * NPIX + h * HWDIM + wbase + r;
                    Vb[pix * CCAT + ch] = f2bf(acc[m][n][r] + bval);
                }
            }
        }
    }
}

// ---------------------------------------------------------------------------
// Kernel 4: neighborhood attention via MFMA over parity tiles.
// Block = 4x4 same-parity query tile; key union = 10x10 pixels.
// QK^T: MFMA M=16 q, N=112 keys (100 valid), K=128 ch.
// Softmax: 16 threads per query over its 49 valid entries.
// PV: VALU from LDS (P broadcast, V rows contiguous).
// ---------------------------------------------------------------------------
#define KPAD 136   // bf16 row pad
#define LGP  114   // f32 logit row pad

__global__ __launch_bounds__(256) void natt_mfma(
        const unsigned short* __restrict__ Qb,
        const unsigned short* __restrict__ Kb,
        const unsigned short* __restrict__ Vb,
        float* __restrict__ out) {
    __shared__ unsigned short Ks[112 * KPAD];
    __shared__ unsigned short Vs[100 * KPAD];
    __shared__ unsigned short Qs[16 * KPAD];
    __shared__ float Lg[16 * LGP];

    int bid = blockIdx.x;
    int tw = bid % 12;
    int th = (bid / 12) % 12;
    int gw = (bid / 144) & 1;
    int gh = (bid / 288) & 1;
    int b  = bid / 576;
    int rh0 = th * 4, rw0 = tw * 4;
    int base_h = min(max(rh0 - 3, 0), 41);
    int base_w = min(max(rw0 - 3, 0), 41);
    int tid = threadIdx.x;

    // ---- stage K (100 px), V (100 px), Q (16 px): 3456 x 16B chunks ----
    for (int c = tid; c < 3456; c += 256) {
        if (c < 3200) {
            int isV = c >= 1600;
            int cc  = isV ? c - 1600 : c;
            int px  = cc >> 4, c8 = cc & 15;
            int ih  = px / 10, iw = px - ih * 10;
            int nh  = gh + 2 * min(base_h + ih, 47);
            int nw2 = gw + 2 * min(base_w + iw, 47);
            int gp  = b * NPIX + nh * HWDIM + nw2;
            uint4 v = *(const uint4*)((isV ? Vb : Kb) + gp * CCAT + c8 * 8);
            *(uint4*)((isV ? Vs : Ks) + px * KPAD + c8 * 8) = v;
        } else {
            int cc = c - 3200;
            int q  = cc >> 4, c8 = cc & 15;
            int qi = q >> 2, qj = q & 3;
            int hh = gh + 2 * (rh0 + qi);
            int ww = gw + 2 * (rw0 + qj);
            int gp = b * NPIX + hh * HWDIM + ww;
            uint4 v = *(const uint4*)(Qb + gp * CCAT + c8 * 8);
            *(uint4*)(Qs + q * KPAD + c8 * 8) = v;
        }
    }
    __syncthreads();

    // ---- QK^T MFMA: wave handles N-tiles wv, wv+4 ----
    int lane = tid & 63;
    int wv   = tid >> 6;
    int lw   = lane & 15;
    int ks8  = (lane >> 4) * 8;
    const float scale = 0.08838834764831845f;

    #pragma unroll
    for (int tt = 0; tt < 2; ++tt) {
        int tile = wv + tt * 4;
        if (tile < 7) {
            f32x4 acc = (f32x4){0.f, 0.f, 0.f, 0.f};
            #pragma unroll
            for (int kk = 0; kk < 4; ++kk) {
                bf16x8 A  = *(const bf16x8*)(Qs + lw * KPAD + kk * 32 + ks8);
                bf16x8 Bf = *(const bf16x8*)(Ks + (tile * 16 + lw) * KPAD + kk * 32 + ks8);
                acc = __builtin_amdgcn_mfma_f32_16x16x32_bf16(A, Bf, acc, 0, 0, 0);
            }
            #pragma unroll
            for (int r = 0; r < 4; ++r) {
                int m = (lane >> 4) * 4 + r;
                Lg[m * LGP + tile * 16 + lw] = acc[r] * scale;
            }
        }
    }
    __syncthreads();

    // ---- softmax: 16 threads per query over 49 valid entries ----
    int q   = tid >> 4, k16 = tid & 15;
    int qi  = q >> 2, qj = q & 3;
    int rh  = rh0 + qi, rw = rw0 + qj;
    int oh  = min(max(rh - 3, 0), 41) - base_h;
    int ow  = min(max(rw - 3, 0), 41) - base_w;

    float ev[4];
    int   en[4];
    float mx = -1e30f;
    #pragma unroll
    for (int u = 0; u < 4; ++u) {
        int idx = k16 + u * 16;
        if (idx < 49) {
            int i = idx / 7, j = idx - i * 7;
            int n = (oh + i) * 10 + ow + j;
            en[u] = n;
            float l = Lg[q * LGP + n];
            ev[u] = l;
            mx = fmaxf(mx, l);
        } else { en[u] = -1; ev[u] = 0.f; }
    }
    #pragma unroll
    for (int off = 8; off > 0; off >>= 1) mx = fmaxf(mx, __shfl_xor(mx, off));
    float s = 0.f;
    #pragma unroll
    for (int u = 0; u < 4; ++u)
        if (en[u] >= 0) { ev[u] = __expf(ev[u] - mx); s += ev[u]; }
    #pragma unroll
    for (int off = 8; off > 0; off >>= 1) s += __shfl_xor(s, off);
    float rs = 1.0f / s;
    #pragma unroll
    for (int u = 0; u < 4; ++u)
        if (en[u] >= 0) Lg[q * LGP + en[u]] = ev[u] * rs;
    // writes/reads below stay within the same 16-lane group's wave: no barrier

    // ---- PV: thread owns (query q, 8 channels) ----
    float o0=0,o1=0,o2=0,o3=0,o4=0,o5=0,o6=0,o7=0;
    int cg = k16 * 8;
    #pragma unroll
    for (int i = 0; i < 7; ++i) {
        int nb = (oh + i) * 10 + ow;
        #pragma unroll
        for (int j = 0; j < 7; ++j) {
            int n = nb + j;
            float p = Lg[q * LGP + n];
            uint4 vvv = *(const uint4*)(Vs + n * KPAD + cg);
            o0 = fmaf(p, bflo(vvv.x), o0); o1 = fmaf(p, bfhi(vvv.x), o1);
            o2 = fmaf(p, bflo(vvv.y), o2); o3 = fmaf(p, bfhi(vvv.y), o3);
            o4 = fmaf(p, bflo(vvv.z), o4); o5 = fmaf(p, bfhi(vvv.z), o5);
            o6 = fmaf(p, bflo(vvv.w), o6); o7 = fmaf(p, bfhi(vvv.w), o7);
        }
    }
    int gp = b * NPIX + (gh + 2 * rh) * HWDIM + (gw + 2 * rw);
    float* op = out + gp * CCAT + cg;
    *(float4*)op       = make_float4(o0, o1, o2, o3);
    *(float4*)(op + 4) = make_float4(o4, o5, o6, o7);
}

// ---------------------------------------------------------------------------
extern "C" void kernel_launch(void* const* d_in, const int* in_sizes, int n_in,
                              void* d_out, int out_size, void* d_ws, size_t ws_size,
                              hipStream_t stream) {
    const float* x  = (const float*)d_in[0];
    const float* wq = (const float*)d_in[1];
    const float* bq = (const float*)d_in[2];
    const float* wk = (const float*)d_in[3];
    const float* bk = (const float*)d_in[4];
    const float* wv = (const float*)d_in[5];
    const float* bv = (const float*)d_in[6];

    unsigned short* ws = (unsigned short*)d_ws;
    unsigned short* Qb  = ws;                              // 2359296 bf16
    unsigned short* Kb  = Qb + BATCH * NPIX * CCAT;
    unsigned short* Vb  = Kb + BATCH * NPIX * CCAT;
    unsigned short* xp  = Vb + BATCH * NPIX * CCAT;        // 2*98*98*64
    unsigned short* wbT = xp + BATCH * PADW * PADW * 64;   // 147456

    hipLaunchKernelGGL(pad_kernel, dim3(BATCH * PADW), dim3(256), 0, stream, x, xp);
    hipLaunchKernelGGL(wb_kernel, dim3(576), dim3(256), 0, stream, wq, wk, wv, wbT);
    hipLaunchKernelGGL(pe_kernel, dim3(4608), dim3(256), 0, stream, Qb, Kb);
    hipLaunchKernelGGL(conv_mfma, dim3(192, 2), dim3(256), 0, stream,
                       xp, wbT, bq, bk, bv, Qb, Kb, Vb);
    hipLaunchKernelGGL(natt_mfma, dim3(1152), dim3(256), 0, stream,
                       Qb, Kb, Vb, (float*)d_out);
}